// Round 1
// baseline (1107.414 us; speedup 1.0000x reference)
//
#include <hip/hip_runtime.h>
#include <math.h>

// Problem constants
#define TT   52        // time steps
#define BBAT 4         // batch
#define CCH  9         // input channels
#define HWP  4096      // 64*64 pixels per image
#define FF   64        // features
#define NP   16384     // b*h*w pixels
#define TD   5         // theta dim
#define NCC  6         // tessellation cells
#define TSTRIDE 147456 // b*c*h*w = 4*9*4096 (stride of t in x)

// output offsets (floats)
#define OUT0 0
#define OUT1 (NP*CCH*TT)        // 7667712  x_shift_pix
#define OUT2 (2*NP*CCH*TT)      // 15335424 theta_pred
#define OUT3 (OUT2 + NP*TD)     // 15417344 theta_shift

// ---------------------------------------------------------------------------
// k_basis: reproduce np.linalg.svd(L) null-space basis (Vt[7:].T) exactly.
// dgesdd path for 7x12, JOBZ='A', N>=MNTHR: LQ factorize (dgelqf), full Q via
// dorglq; rows 8..12 of VT are rows 8..12 of Q = e_{8..12}^T * H(7)...H(1).
// Lane k (k<12) owns column k of everything; f64 throughout.
// ---------------------------------------------------------------------------
__global__ void k_basis(float* __restrict__ Bout) {
    int k = threadIdx.x;  // 64 lanes, cols 0..11 active
    double Acol[7], Vcol[7], Mcol[5];
#pragma unroll
    for (int r = 0; r < 7; r++) { Acol[r] = 0.0; Vcol[r] = 0.0; }
#pragma unroll
    for (int j = 0; j < 5; j++) Mcol[j] = 0.0;

    if (k < 12) {
        // build L columns: continuity rows + boundary rows
#pragma unroll
        for (int j = 1; j < 6; j++) {
            int r = j - 1;
            double xj = (double)j / 6.0;
            if (k == 2 * (j - 1))     Acol[r] = xj;
            if (k == 2 * (j - 1) + 1) Acol[r] = 1.0;
            if (k == 2 * j)           Acol[r] = -xj;
            if (k == 2 * j + 1)       Acol[r] = -1.0;
        }
        if (k == 1)  Acol[5] = 1.0;
        if (k == 10) Acol[6] = 1.0;
        if (k == 11) Acol[6] = 1.0;
#pragma unroll
        for (int j = 0; j < 5; j++) Mcol[j] = (k == 7 + j) ? 1.0 : 0.0;
    }

    double tau[7];
#pragma unroll
    for (int i = 0; i < 7; i++) {
        // xnorm^2 over k>i
        double c = (k > i && k < 12) ? Acol[i] * Acol[i] : 0.0;
#pragma unroll
        for (int off = 1; off < 64; off <<= 1) c += __shfl_xor(c, off, 64);
        double alpha = __shfl(Acol[i], i, 64);
        double t_i, vk;
        if (c == 0.0) {
            t_i = 0.0;
            vk = (k == i) ? 1.0 : 0.0;
        } else {
            double nrm  = sqrt(alpha * alpha + c);
            double beta = (alpha >= 0.0) ? -nrm : nrm;  // Fortran SIGN convention
            t_i = (beta - alpha) / beta;
            double inv = 1.0 / (alpha - beta);
            vk = (k == i) ? 1.0 : ((k > i && k < 12) ? Acol[i] * inv : 0.0);
        }
        tau[i]  = t_i;
        Vcol[i] = vk;
        // apply H(i) from the right to rows r>i
#pragma unroll
        for (int r = 0; r < 7; r++) {
            if (r > i) {
                double w = Acol[r] * vk;
#pragma unroll
                for (int off = 1; off < 64; off <<= 1) w += __shfl_xor(w, off, 64);
                Acol[r] -= t_i * w * vk;
            }
        }
    }
    // rows e_{8..12}: apply H(7) then H(6) ... then H(1)  (M := M*H(7)...H(1))
#pragma unroll
    for (int i = 6; i >= 0; i--) {
#pragma unroll
        for (int j = 0; j < 5; j++) {
            double w = Mcol[j] * Vcol[i];
#pragma unroll
            for (int off = 1; off < 64; off <<= 1) w += __shfl_xor(w, off, 64);
            Mcol[j] -= tau[i] * w * Vcol[i];
        }
    }
    if (k < 12) {
#pragma unroll
        for (int j = 0; j < 5; j++) Bout[k * 5 + j] = (float)Mcol[j];
    }
}

// ---------------------------------------------------------------------------
// theta_shift output: 0.5 * raw
// ---------------------------------------------------------------------------
__global__ void k_theta_shift(const float* __restrict__ raw, float* __restrict__ out) {
    int i = blockIdx.x * blockDim.x + threadIdx.x;
    if (i < NP * TD) out[i] = 0.5f * raw[i];
}

// ---------------------------------------------------------------------------
// k_cpab: per (pixel n, grid point tt): build per-cell (a,b) from theta@B^T,
// 100 Euler steps, then lerp the 9 channels of x_pix at the warped position.
// Writes out[n*468 + ch*52 + tt].
// ---------------------------------------------------------------------------
__global__ __launch_bounds__(256) void k_cpab(
    const float* __restrict__ x,      // [52,4,9,64,64]
    const float* __restrict__ theta,  // [N,5]
    const float* __restrict__ Bf,     // [12,5]
    float scale,
    float* __restrict__ out)          // [N,9,52]
{
    int gid = blockIdx.x * blockDim.x + threadIdx.x;
    if (gid >= NP * TT) return;
    int n = gid / TT, tt = gid % TT;

    float th[TD];
#pragma unroll
    for (int j = 0; j < TD; j++) th[j] = scale * theta[n * TD + j];

    float a[NCC], b[NCC];
#pragma unroll
    for (int i = 0; i < NCC; i++) {
        float aa = 0.f, bb = 0.f;
#pragma unroll
        for (int j = 0; j < TD; j++) {
            aa += th[j] * Bf[(2 * i) * TD + j];
            bb += th[j] * Bf[(2 * i + 1) * TD + j];
        }
        a[i] = aa; b[i] = bb;
    }

    float xc = (float)tt / 51.0f;
    for (int s = 0; s < 100; ++s) {
        float t6 = xc * 6.0f;
        float av = t6 < 1.f ? a[0] : t6 < 2.f ? a[1] : t6 < 3.f ? a[2]
                 : t6 < 4.f ? a[3] : t6 < 5.f ? a[4] : a[5];
        float bv = t6 < 1.f ? b[0] : t6 < 2.f ? b[1] : t6 < 3.f ? b[2]
                 : t6 < 4.f ? b[3] : t6 < 5.f ? b[4] : b[5];
        xc = xc + 0.01f * (av * xc + bv);
        xc = fminf(fmaxf(xc, 0.0f), 1.0f);
    }

    // interpolate 9 channels
    float pos = xc * 51.0f;
    int x0 = (int)floorf(pos);
    if (x0 < 0) x0 = 0;
    if (x0 > 50) x0 = 50;
    float w = pos - (float)x0;
    int bb_ = n >> 12, p = n & 4095;
    int base0 = ((x0 * BBAT + bb_) * CCH) * HWP + p;
#pragma unroll
    for (int ch = 0; ch < CCH; ++ch) {
        float d0 = x[base0 + ch * HWP];
        float d1 = x[base0 + ch * HWP + TSTRIDE];
        out[n * (CCH * TT) + ch * TT + tt] = d0 * (1.0f - w) + d1 * w;
    }
}

// ---------------------------------------------------------------------------
// k_loc: fused localise(orig) + localise(shift) + fc1 + fc2 + tanh.
// 4 waves/block, wave w handles pixel n = blockIdx*4 + w. Lane = feature f.
// Per position (branch,tt): LN9 -> conv1(relu) -> conv2(relu, weights in
// regs) -> LN64 (shfl butterfly) -> fc1 partial accum (weights staged to LDS
// transposed [16][64], shared by the 4 waves).
// ---------------------------------------------------------------------------
__global__ __launch_bounds__(256) void k_loc(
    const float* __restrict__ x,    // [52,4,9,64,64]
    const float* __restrict__ xs,   // x_shift_pix [N,9,52]
    const float* __restrict__ lniw, const float* __restrict__ lnib,
    const float* __restrict__ w1c,  const float* __restrict__ b1c,
    const float* __restrict__ w2c,  const float* __restrict__ b2c,
    const float* __restrict__ lncw, const float* __restrict__ lncb,
    const float* __restrict__ fc1w, const float* __restrict__ fc1b,
    const float* __restrict__ fc2w, const float* __restrict__ fc2b,
    float* __restrict__ outtheta)   // [N,5]
{
    __shared__ float y1L[4][64];
    __shared__ float w1T[16][64];   // staged fc1 rows, transposed: [j][f]
    __shared__ float lnin[2][9];

    int tid  = threadIdx.x;
    int lane = tid & 63;
    int wv   = tid >> 6;
    int n    = blockIdx.x * 4 + wv;
    int bb_  = n >> 12, p = n & 4095;

    if (tid < 9) { lnin[0][tid] = lniw[tid]; lnin[1][tid] = lnib[tid]; }

    // per-lane weights
    float w2col[64];
#pragma unroll
    for (int f = 0; f < 64; ++f) w2col[f] = w2c[f * 64 + lane];
    float w1cr[9];
#pragma unroll
    for (int c = 0; c < 9; ++c) w1cr[c] = w1c[c * 64 + lane];
    float b1r = b1c[lane], b2r = b2c[lane];
    float lnwr = lncw[lane], lnbr = lncb[lane];

    float acc[16];
#pragma unroll
    for (int j = 0; j < 16; ++j) acc[j] = 0.f;

    int sf = tid & 63;   // staging: row f
    int sw = tid >> 6;   // staging: quarter (j-group)

    __syncthreads();

    for (int beta = 0; beta < 2; ++beta) {
        for (int tt = 0; tt < TT; ++tt) {
            // issue fc1-row stage load early (hidden under LN/conv1)
            int srow = beta * 3328 + sf * TT + tt;
            float4 wst = *(const float4*)(fc1w + srow * 16 + sw * 4);

            // load 9 channels (wave-uniform addresses)
            float xin[9];
            if (beta == 0) {
                int base = ((tt * BBAT + bb_) * CCH) * HWP + p;
#pragma unroll
                for (int c = 0; c < 9; ++c) xin[c] = x[base + c * HWP];
            } else {
                int base = n * (CCH * TT) + tt;
#pragma unroll
                for (int c = 0; c < 9; ++c) xin[c] = xs[base + c * TT];
            }
            // LN over 9 channels (two-pass, per ref)
            float s = 0.f;
#pragma unroll
            for (int c = 0; c < 9; ++c) s += xin[c];
            float m = s * (1.0f / 9.0f);
            float v = 0.f;
#pragma unroll
            for (int c = 0; c < 9; ++c) { float d = xin[c] - m; v += d * d; }
            v *= (1.0f / 9.0f);
            float rs = rsqrtf(v + 1e-5f);
            // conv1 (this lane's feature)
            float y1 = b1r;
#pragma unroll
            for (int c = 0; c < 9; ++c) {
                float z = (xin[c] - m) * rs * lnin[0][c] + lnin[1][c];
                y1 += z * w1cr[c];
            }
            y1 = fmaxf(y1, 0.f);
            y1L[wv][lane] = y1;

            // write staged fc1 rows transposed (bank-conflict-free both ways)
            w1T[sw * 4 + 0][sf] = wst.x;
            w1T[sw * 4 + 1][sf] = wst.y;
            w1T[sw * 4 + 2][sf] = wst.z;
            w1T[sw * 4 + 3][sf] = wst.w;
            __syncthreads();

            // conv2: y2[lane] = b2 + sum_f y1[f]*W2[f][lane]
            float y2 = b2r;
            const float4* y1v = (const float4*)y1L[wv];
#pragma unroll
            for (int k = 0; k < 16; ++k) {
                float4 yv = y1v[k];
                y2 += yv.x * w2col[4 * k + 0] + yv.y * w2col[4 * k + 1]
                    + yv.z * w2col[4 * k + 2] + yv.w * w2col[4 * k + 3];
            }
            y2 = fmaxf(y2, 0.f);

            // LN64 (two-pass via butterfly)
            float ssum = y2;
#pragma unroll
            for (int off = 1; off < 64; off <<= 1) ssum += __shfl_xor(ssum, off, 64);
            float m2 = ssum * (1.0f / 64.0f);
            float d2 = y2 - m2;
            float ssq = d2 * d2;
#pragma unroll
            for (int off = 1; off < 64; off <<= 1) ssq += __shfl_xor(ssq, off, 64);
            float v2 = ssq * (1.0f / 64.0f);
            float z2 = d2 * rsqrtf(v2 + 1e-5f) * lnwr + lnbr;

            // fc1 partial accumulation
#pragma unroll
            for (int j = 0; j < 16; ++j) acc[j] += z2 * w1T[j][lane];
            __syncthreads();
        }
    }

    // reduce acc over lanes (butterfly -> all lanes hold totals)
#pragma unroll
    for (int j = 0; j < 16; ++j) {
        float aj = acc[j];
#pragma unroll
        for (int off = 1; off < 64; off <<= 1) aj += __shfl_xor(aj, off, 64);
        acc[j] = aj;
    }
    // fc2 + tanh: lanes 0..4 each produce one theta component
    if (lane < TD) {
        float o = fc2b[lane];
#pragma unroll
        for (int j = 0; j < 16; ++j) {
            float hj = fmaxf(acc[j] + fc1b[j], 0.f);
            o += hj * fc2w[j * TD + lane];
        }
        outtheta[n * TD + lane] = tanhf(o);
    }
}

// ---------------------------------------------------------------------------
extern "C" void kernel_launch(void* const* d_in, const int* in_sizes, int n_in,
                              void* d_out, int out_size, void* d_ws, size_t ws_size,
                              hipStream_t stream) {
    const float* x     = (const float*)d_in[0];
    const float* thraw = (const float*)d_in[1];
    const float* lniw  = (const float*)d_in[2];
    const float* lnib  = (const float*)d_in[3];
    const float* w1c   = (const float*)d_in[4];
    const float* b1c   = (const float*)d_in[5];
    const float* w2c   = (const float*)d_in[6];
    const float* b2c   = (const float*)d_in[7];
    const float* lncw  = (const float*)d_in[8];
    const float* lncb  = (const float*)d_in[9];
    const float* fc1w  = (const float*)d_in[10];
    const float* fc1b  = (const float*)d_in[11];
    const float* fc2w  = (const float*)d_in[12];
    const float* fc2b  = (const float*)d_in[13];
    float* out = (float*)d_out;
    float* Bf  = (float*)d_ws;  // 60 floats

    hipLaunchKernelGGL(k_basis, dim3(1), dim3(64), 0, stream, Bf);
    hipLaunchKernelGGL(k_theta_shift, dim3((NP * TD + 255) / 256), dim3(256), 0, stream,
                       thraw, out + OUT3);
    hipLaunchKernelGGL(k_cpab, dim3((NP * TT) / 256), dim3(256), 0, stream,
                       x, thraw, Bf, 0.5f, out + OUT1);
    hipLaunchKernelGGL(k_loc, dim3(NP / 4), dim3(256), 0, stream,
                       x, out + OUT1, lniw, lnib, w1c, b1c, w2c, b2c, lncw, lncb,
                       fc1w, fc1b, fc2w, fc2b, out + OUT2);
    hipLaunchKernelGGL(k_cpab, dim3((NP * TT) / 256), dim3(256), 0, stream,
                       x, out + OUT2, Bf, 1.0f, out + OUT0);
}

// Round 2
// 966.903 us; speedup vs baseline: 1.1453x; 1.1453x over previous
//
#include <hip/hip_runtime.h>
#include <math.h>

// Problem constants
#define TT   52        // time steps
#define BBAT 4         // batch
#define CCH  9         // input channels
#define HWP  4096      // 64*64 pixels per image
#define FF   64        // features
#define NP   16384     // b*h*w pixels
#define TD   5         // theta dim
#define NCC  6         // tessellation cells
#define TSTRIDE 147456 // b*c*h*w = 4*9*4096 (stride of t in x)

// output offsets (floats)
#define OUT0 0
#define OUT1 (NP*CCH*TT)        // 7667712  x_shift_pix
#define OUT2 (2*NP*CCH*TT)      // 15335424 theta_pred
#define OUT3 (OUT2 + NP*TD)     // 15417344 theta_shift

// ---------------------------------------------------------------------------
// k_basis: reproduce np.linalg.svd(L) null-space basis (Vt[7:].T) exactly.
// (dgesdd LQ path; rows 8..12 of VT = e_{8..12}^T * H(7)...H(1).)
// ---------------------------------------------------------------------------
__global__ void k_basis(float* __restrict__ Bout) {
    int k = threadIdx.x;  // 64 lanes, cols 0..11 active
    double Acol[7], Vcol[7], Mcol[5];
#pragma unroll
    for (int r = 0; r < 7; r++) { Acol[r] = 0.0; Vcol[r] = 0.0; }
#pragma unroll
    for (int j = 0; j < 5; j++) Mcol[j] = 0.0;

    if (k < 12) {
#pragma unroll
        for (int j = 1; j < 6; j++) {
            int r = j - 1;
            double xj = (double)j / 6.0;
            if (k == 2 * (j - 1))     Acol[r] = xj;
            if (k == 2 * (j - 1) + 1) Acol[r] = 1.0;
            if (k == 2 * j)           Acol[r] = -xj;
            if (k == 2 * j + 1)       Acol[r] = -1.0;
        }
        if (k == 1)  Acol[5] = 1.0;
        if (k == 10) Acol[6] = 1.0;
        if (k == 11) Acol[6] = 1.0;
#pragma unroll
        for (int j = 0; j < 5; j++) Mcol[j] = (k == 7 + j) ? 1.0 : 0.0;
    }

    double tau[7];
#pragma unroll
    for (int i = 0; i < 7; i++) {
        double c = (k > i && k < 12) ? Acol[i] * Acol[i] : 0.0;
#pragma unroll
        for (int off = 1; off < 64; off <<= 1) c += __shfl_xor(c, off, 64);
        double alpha = __shfl(Acol[i], i, 64);
        double t_i, vk;
        if (c == 0.0) {
            t_i = 0.0;
            vk = (k == i) ? 1.0 : 0.0;
        } else {
            double nrm  = sqrt(alpha * alpha + c);
            double beta = (alpha >= 0.0) ? -nrm : nrm;  // Fortran SIGN convention
            t_i = (beta - alpha) / beta;
            double inv = 1.0 / (alpha - beta);
            vk = (k == i) ? 1.0 : ((k > i && k < 12) ? Acol[i] * inv : 0.0);
        }
        tau[i]  = t_i;
        Vcol[i] = vk;
#pragma unroll
        for (int r = 0; r < 7; r++) {
            if (r > i) {
                double w = Acol[r] * vk;
#pragma unroll
                for (int off = 1; off < 64; off <<= 1) w += __shfl_xor(w, off, 64);
                Acol[r] -= t_i * w * vk;
            }
        }
    }
#pragma unroll
    for (int i = 6; i >= 0; i--) {
#pragma unroll
        for (int j = 0; j < 5; j++) {
            double w = Mcol[j] * Vcol[i];
#pragma unroll
            for (int off = 1; off < 64; off <<= 1) w += __shfl_xor(w, off, 64);
            Mcol[j] -= tau[i] * w * Vcol[i];
        }
    }
    if (k < 12) {
#pragma unroll
        for (int j = 0; j < 5; j++) Bout[k * 5 + j] = (float)Mcol[j];
    }
}

// ---------------------------------------------------------------------------
__global__ void k_theta_shift(const float* __restrict__ raw, float* __restrict__ out) {
    int i = blockIdx.x * blockDim.x + threadIdx.x;
    if (i < NP * TD) out[i] = 0.5f * raw[i];
}

// ---------------------------------------------------------------------------
// k_cpab: per (pixel n, grid point tt): theta@B^T -> per-cell (a,b),
// 100 Euler steps, lerp 9 channels.
// ---------------------------------------------------------------------------
__global__ __launch_bounds__(256) void k_cpab(
    const float* __restrict__ x,      // [52,4,9,64,64]
    const float* __restrict__ theta,  // [N,5]
    const float* __restrict__ Bf,     // [12,5]
    float scale,
    float* __restrict__ out)          // [N,9,52]
{
    int gid = blockIdx.x * blockDim.x + threadIdx.x;
    if (gid >= NP * TT) return;
    int n = gid / TT, tt = gid % TT;

    float th[TD];
#pragma unroll
    for (int j = 0; j < TD; j++) th[j] = scale * theta[n * TD + j];

    float a[NCC], b[NCC];
#pragma unroll
    for (int i = 0; i < NCC; i++) {
        float aa = 0.f, bb = 0.f;
#pragma unroll
        for (int j = 0; j < TD; j++) {
            aa += th[j] * Bf[(2 * i) * TD + j];
            bb += th[j] * Bf[(2 * i + 1) * TD + j];
        }
        a[i] = aa; b[i] = bb;
    }

    float xc = (float)tt / 51.0f;
    for (int s = 0; s < 100; ++s) {
        float t6 = xc * 6.0f;
        float av = t6 < 1.f ? a[0] : t6 < 2.f ? a[1] : t6 < 3.f ? a[2]
                 : t6 < 4.f ? a[3] : t6 < 5.f ? a[4] : a[5];
        float bv = t6 < 1.f ? b[0] : t6 < 2.f ? b[1] : t6 < 3.f ? b[2]
                 : t6 < 4.f ? b[3] : t6 < 5.f ? b[4] : b[5];
        xc = xc + 0.01f * (av * xc + bv);
        xc = fminf(fmaxf(xc, 0.0f), 1.0f);
    }

    float pos = xc * 51.0f;
    int x0 = (int)floorf(pos);
    if (x0 < 0) x0 = 0;
    if (x0 > 50) x0 = 50;
    float w = pos - (float)x0;
    int bb_ = n >> 12, p = n & 4095;
    int base0 = ((x0 * BBAT + bb_) * CCH) * HWP + p;
#pragma unroll
    for (int ch = 0; ch < CCH; ++ch) {
        float d0 = x[base0 + ch * HWP];
        float d1 = x[base0 + ch * HWP + TSTRIDE];
        out[n * (CCH * TT) + ch * TT + tt] = d0 * (1.0f - w) + d1 * w;
    }
}

// ---------------------------------------------------------------------------
// k_loc: fused localise(orig)+localise(shift)+fc1+fc2+tanh, software-pipelined.
// 4 waves/block, wave wv = pixel blockIdx*4+wv, lane = feature f.
// Pipeline: one barrier/iter; w1T double-buffered; next-pos xin + fc1w row
// prefetched into regs at iter start (latency hidden under compute).
// y1 exchange via per-wave LDS (no barrier: intra-wave lgkmcnt ordering).
// conv1 folded with LN_in: y1 = relu(bias0 + rs*(dot9 - m*sA)).
// ---------------------------------------------------------------------------
__global__ __launch_bounds__(256) void k_loc(
    const float* __restrict__ x,    // [52,4,9,64,64]
    const float* __restrict__ xs,   // x_shift_pix [N,9,52]
    const float* __restrict__ lniw, const float* __restrict__ lnib,
    const float* __restrict__ w1c,  const float* __restrict__ b1c,
    const float* __restrict__ w2c,  const float* __restrict__ b2c,
    const float* __restrict__ lncw, const float* __restrict__ lncb,
    const float* __restrict__ fc1w, const float* __restrict__ fc1b,
    const float* __restrict__ fc2w, const float* __restrict__ fc2b,
    float* __restrict__ outtheta)   // [N,5]
{
    __shared__ float y1L[4][64];        // per-wave y1 broadcast (no barrier)
    __shared__ float w1T[2][16][64];    // double-buffered fc1 rows, [j][f]

    int tid  = threadIdx.x;
    int lane = tid & 63;
    int wv   = tid >> 6;
    int n    = blockIdx.x * 4 + wv;
    int bb_  = n >> 12, p = n & 4095;
    int sf   = lane;    // staging: feature row
    int sw   = wv;      // staging: j-quarter

    // per-lane weights (resident for kernel lifetime)
    float w2col[64];
#pragma unroll
    for (int f = 0; f < 64; ++f) w2col[f] = w2c[f * 64 + lane];
    float wA[9];
    float bias0 = b1c[lane], sA = 0.f;
#pragma unroll
    for (int c = 0; c < 9; ++c) {
        float wr = w1c[c * 64 + lane];
        wA[c] = lniw[c] * wr;
        bias0 += lnib[c] * wr;
        sA += wA[c];
    }
    float b2r  = b2c[lane];
    float lnwr = lncw[lane], lnbr = lncb[lane];

    float acc[16];
#pragma unroll
    for (int j = 0; j < 16; ++j) acc[j] = 0.f;

    // prologue: load pos 0 inputs, stage w1T[0]
    float xin[9];
    {
        int base = ((0 * BBAT + bb_) * CCH) * HWP + p;
#pragma unroll
        for (int c = 0; c < 9; ++c) xin[c] = x[base + c * HWP];
        int srow = sf * TT + 0;
        float4 w0 = *(const float4*)(fc1w + srow * 16 + sw * 4);
        w1T[0][sw * 4 + 0][sf] = w0.x;
        w1T[0][sw * 4 + 1][sf] = w0.y;
        w1T[0][sw * 4 + 2][sf] = w0.z;
        w1T[0][sw * 4 + 3][sf] = w0.w;
    }
    __syncthreads();

    for (int pos = 0; pos < 2 * TT; ++pos) {
        int buf = pos & 1;
        int pn  = pos + 1;
        // ---- prefetch next position (regs) ----
        float xnx[9];
        float4 wnx;
        if (pn < 2 * TT) {
            int betan = (pn >= TT) ? 1 : 0;
            int ttn   = pn - betan * TT;
            if (!betan) {
                int base = ((ttn * BBAT + bb_) * CCH) * HWP + p;
#pragma unroll
                for (int c = 0; c < 9; ++c) xnx[c] = x[base + c * HWP];
            } else {
                int base = n * (CCH * TT) + ttn;
#pragma unroll
                for (int c = 0; c < 9; ++c) xnx[c] = xs[base + c * TT];
            }
            int srow = betan * (FF * TT) + sf * TT + ttn;
            wnx = *(const float4*)(fc1w + srow * 16 + sw * 4);
        }

        // ---- LN9 + conv1 (folded) ----
        float s1 = 0.f, s2 = 0.f, d9 = 0.f;
#pragma unroll
        for (int c = 0; c < 9; ++c) {
            s1 += xin[c];
            s2 += xin[c] * xin[c];
            d9 += xin[c] * wA[c];
        }
        float m = s1 * (1.0f / 9.0f);
        float v = fmaxf(s2 * (1.0f / 9.0f) - m * m, 0.f);
        float rs = rsqrtf(v + 1e-5f);
        float y1 = fmaxf(bias0 + rs * (d9 - m * sA), 0.f);
        y1L[wv][lane] = y1;

        // ---- conv2 (4 independent chains) ----
        float a0 = b2r, a1 = 0.f, a2 = 0.f, a3 = 0.f;
        const float4* y1v = (const float4*)y1L[wv];
#pragma unroll
        for (int k = 0; k < 16; ++k) {
            float4 yv = y1v[k];
            a0 += yv.x * w2col[4 * k + 0];
            a1 += yv.y * w2col[4 * k + 1];
            a2 += yv.z * w2col[4 * k + 2];
            a3 += yv.w * w2col[4 * k + 3];
        }
        float y2 = fmaxf((a0 + a1) + (a2 + a3), 0.f);

        // ---- LN64 (fused mean/var, interleaved butterflies) ----
        float bs = y2, bq = y2 * y2;
#pragma unroll
        for (int off = 1; off < 64; off <<= 1) {
            bs += __shfl_xor(bs, off, 64);
            bq += __shfl_xor(bq, off, 64);
        }
        float m2 = bs * (1.0f / 64.0f);
        float v2 = fmaxf(bq * (1.0f / 64.0f) - m2 * m2, 0.f);
        float z2 = (y2 - m2) * rsqrtf(v2 + 1e-5f) * lnwr + lnbr;

        // ---- fc1 partial accumulation (reads current buffer) ----
#pragma unroll
        for (int j = 0; j < 16; ++j) acc[j] += z2 * w1T[buf][j][lane];

        // ---- stage next buffer, advance pipeline ----
        if (pn < 2 * TT) {
            w1T[buf ^ 1][sw * 4 + 0][sf] = wnx.x;
            w1T[buf ^ 1][sw * 4 + 1][sf] = wnx.y;
            w1T[buf ^ 1][sw * 4 + 2][sf] = wnx.z;
            w1T[buf ^ 1][sw * 4 + 3][sf] = wnx.w;
#pragma unroll
            for (int c = 0; c < 9; ++c) xin[c] = xnx[c];
        }
        __syncthreads();
    }

    // reduce acc over lanes (butterfly -> all lanes hold totals)
#pragma unroll
    for (int j = 0; j < 16; ++j) {
        float aj = acc[j];
#pragma unroll
        for (int off = 1; off < 64; off <<= 1) aj += __shfl_xor(aj, off, 64);
        acc[j] = aj;
    }
    // fc2 + tanh
    if (lane < TD) {
        float o = fc2b[lane];
#pragma unroll
        for (int j = 0; j < 16; ++j) {
            float hj = fmaxf(acc[j] + fc1b[j], 0.f);
            o += hj * fc2w[j * TD + lane];
        }
        outtheta[n * TD + lane] = tanhf(o);
    }
}

// ---------------------------------------------------------------------------
extern "C" void kernel_launch(void* const* d_in, const int* in_sizes, int n_in,
                              void* d_out, int out_size, void* d_ws, size_t ws_size,
                              hipStream_t stream) {
    const float* x     = (const float*)d_in[0];
    const float* thraw = (const float*)d_in[1];
    const float* lniw  = (const float*)d_in[2];
    const float* lnib  = (const float*)d_in[3];
    const float* w1c   = (const float*)d_in[4];
    const float* b1c   = (const float*)d_in[5];
    const float* w2c   = (const float*)d_in[6];
    const float* b2c   = (const float*)d_in[7];
    const float* lncw  = (const float*)d_in[8];
    const float* lncb  = (const float*)d_in[9];
    const float* fc1w  = (const float*)d_in[10];
    const float* fc1b  = (const float*)d_in[11];
    const float* fc2w  = (const float*)d_in[12];
    const float* fc2b  = (const float*)d_in[13];
    float* out = (float*)d_out;
    float* Bf  = (float*)d_ws;  // 60 floats

    hipLaunchKernelGGL(k_basis, dim3(1), dim3(64), 0, stream, Bf);
    hipLaunchKernelGGL(k_theta_shift, dim3((NP * TD + 255) / 256), dim3(256), 0, stream,
                       thraw, out + OUT3);
    hipLaunchKernelGGL(k_cpab, dim3((NP * TT) / 256), dim3(256), 0, stream,
                       x, thraw, Bf, 0.5f, out + OUT1);
    hipLaunchKernelGGL(k_loc, dim3(NP / 4), dim3(256), 0, stream,
                       x, out + OUT1, lniw, lnib, w1c, b1c, w2c, b2c, lncw, lncb,
                       fc1w, fc1b, fc2w, fc2b, out + OUT2);
    hipLaunchKernelGGL(k_cpab, dim3((NP * TT) / 256), dim3(256), 0, stream,
                       x, out + OUT2, Bf, 1.0f, out + OUT0);
}